// Round 12
// baseline (1235.349 us; speedup 1.0000x reference)
//
#include <hip/hip_runtime.h>

// ---------------------------------------------------------------------------
// DeepProteinClassifier, mask-compacted, attention fused end-to-end:
//   scan_mask -> compact_x -> QKV gemm -> attn_fused (scores+softmax+PV,
//   P kept in LDS, V read direct from L2/L3, ctx written in-place over Qb)
//   -> LN+pool -> MLP.
// GEMM: m97-structure gemm128s (BK=32, single 16KB LDS, ~8 blocks/CU TLP).
// attn_fused<NKS>: NKS in {4,6,8} brackets nks=ceil128(cnt); QK dbuf LDS
// (16KB*NKS) is reused as P[64][NKS*128] bf16 for the PV phase.
// ---------------------------------------------------------------------------

#define DEVINL __device__ __forceinline__

typedef __attribute__((ext_vector_type(8))) short bf16x8;
typedef __attribute__((ext_vector_type(4))) float f32x4;
typedef __attribute__((ext_vector_type(4))) unsigned short u16x4;

DEVINL unsigned short f2bf(float f) {
  unsigned int u = __float_as_uint(f);
  u += 0x7FFFu + ((u >> 16) & 1u);  // round-to-nearest-even
  return (unsigned short)(u >> 16);
}

DEVINL float bf2f(unsigned short h) { return __uint_as_float(((unsigned int)h) << 16); }

DEVINL void gload_lds16(const void* g, void* l) {
  __builtin_amdgcn_global_load_lds((const __attribute__((address_space(1))) unsigned int*)g,
                                   (__attribute__((address_space(3))) unsigned int*)l,
                                   16, 0, 0);
}

#define MFMA16(a, b, c) __builtin_amdgcn_mfma_f32_16x16x32_bf16((a), (b), (c), 0, 0, 0)

// ---------------------------------------------------------------------------
// Per-b prefix scan of mask: idx[b][j] = s of j-th unmasked row; cnt[b].
// ---------------------------------------------------------------------------
__global__ __launch_bounds__(256) void scan_mask(
    const int* __restrict__ mask, int* __restrict__ idx, int* __restrict__ cnt) {
  __shared__ int ps[256];
  const int b = blockIdx.x, t = threadIdx.x;
  const int4 m = *(const int4*)(mask + b * 1024 + t * 4);
  const int s = (m.x != 0) + (m.y != 0) + (m.z != 0) + (m.w != 0);
  ps[t] = s;
  __syncthreads();
  for (int off = 1; off < 256; off <<= 1) {
    const int v = (t >= off) ? ps[t - off] : 0;
    __syncthreads();
    ps[t] += v;
    __syncthreads();
  }
  int pos = ps[t] - s;
  if (m.x) idx[b * 1024 + pos++] = t * 4 + 0;
  if (m.y) idx[b * 1024 + pos++] = t * 4 + 1;
  if (m.z) idx[b * 1024 + pos++] = t * 4 + 2;
  if (m.w) idx[b * 1024 + pos++] = t * 4 + 3;
  if (t == 255) cnt[b] = ps[255];
}

// ---------------------------------------------------------------------------
// Build Wqkv [3072][1024] bf16 + biasQKV[2880] f32 (Q pre-scaled).
// ---------------------------------------------------------------------------
__global__ __launch_bounds__(256) void cast_wqkv(
    const float* __restrict__ Wq, const float* __restrict__ Wk, const float* __restrict__ Wv,
    const float* __restrict__ bq, const float* __restrict__ bk, const float* __restrict__ bv,
    unsigned short* __restrict__ Wqkv, float* __restrict__ biasQ, float scaleQ) {
  const int r = blockIdx.x, t = threadIdx.x;
  const int seg = (r >= 1920) ? 2 : (r >= 960 ? 1 : 0);
  const int sr = r - seg * 960;
  const float* W = (seg == 0) ? Wq : (seg == 1) ? Wk : Wv;
  const float sc = (seg == 0) ? scaleQ : 1.0f;
  if (t < 240) {
    f32x4 v = *(const f32x4*)(W + (size_t)sr * 960 + t * 4);
    u16x4 o;
    o[0] = f2bf(v[0] * sc); o[1] = f2bf(v[1] * sc);
    o[2] = f2bf(v[2] * sc); o[3] = f2bf(v[3] * sc);
    *(u16x4*)(Wqkv + (size_t)r * 1024 + t * 4) = o;
  } else {
    u16x4 z = {};
    *(u16x4*)(Wqkv + (size_t)r * 1024 + 960 + (t - 240) * 4) = z;
  }
  if (t == 0) {
    const float* bb = (seg == 0) ? bq : (seg == 1) ? bk : bv;
    biasQ[r] = bb[sr] * sc;
  }
}

// ---------------------------------------------------------------------------
// Gather-compact-cast: xc[b][j] = bf16(x[b][idx[b][j]]) for j < cnt[b];
// zero rows j in [cnt, ceil128(cnt)); 1024 cols (960 data + 64 zero pad).
// ---------------------------------------------------------------------------
__global__ __launch_bounds__(256) void compact_x(
    const float* __restrict__ x, const int* __restrict__ idx, const int* __restrict__ cnt,
    unsigned short* __restrict__ xc) {
  const int b = blockIdx.y;
  const int j = blockIdx.x * 4 + (threadIdx.x >> 6);
  const int l = threadIdx.x & 63;
  const int cb = cnt[b];
  const int cbc = (cb + 127) & ~127;
  if (j >= cbc) return;
  unsigned short* o = xc + ((size_t)b * 1024 + j) * 1024 + l * 16;
  bf16x8 o0 = {}, o1 = {};
  if (j < cb && l < 60) {
    const int s = idx[b * 1024 + j];
    const float* g = x + ((size_t)b * 1024 + s) * 960 + l * 16;
    f32x4 v0 = *(const f32x4*)(g);
    f32x4 v1 = *(const f32x4*)(g + 4);
    f32x4 v2 = *(const f32x4*)(g + 8);
    f32x4 v3 = *(const f32x4*)(g + 12);
    o0[0] = (short)f2bf(v0[0]); o0[1] = (short)f2bf(v0[1]);
    o0[2] = (short)f2bf(v0[2]); o0[3] = (short)f2bf(v0[3]);
    o0[4] = (short)f2bf(v1[0]); o0[5] = (short)f2bf(v1[1]);
    o0[6] = (short)f2bf(v1[2]); o0[7] = (short)f2bf(v1[3]);
    o1[0] = (short)f2bf(v2[0]); o1[1] = (short)f2bf(v2[1]);
    o1[2] = (short)f2bf(v2[2]); o1[3] = (short)f2bf(v2[3]);
    o1[4] = (short)f2bf(v3[0]); o1[5] = (short)f2bf(v3[1]);
    o1[6] = (short)f2bf(v3[2]); o1[7] = (short)f2bf(v3[3]);
  }
  *(bf16x8*)(o) = o0;
  *(bf16x8*)(o + 8) = o1;
}

// ---------------------------------------------------------------------------
// gemm128s: 128x128 NT GEMM, m97 structure (BK=32, single 16KB LDS, 4 waves,
// plain __syncthreads). (row>>1)&3 slot swizzle. Per-b compaction via cntArr.
// QKV epilogue: bf16 +bias -> Qb/Kb/Vt-transposed (V-stores merged u16x4).
// ---------------------------------------------------------------------------
__global__ __launch_bounds__(256, 4) void gemm128s(
    const unsigned short* __restrict__ Ap, const unsigned short* __restrict__ Bp,
    int lda, int ldb, const float* __restrict__ bias,
    unsigned short* __restrict__ outQ, unsigned short* __restrict__ outK,
    unsigned short* __restrict__ outV,
    int mTiles, int nTiles, int nktFixed, int ncols,
    size_t aStride, const int* __restrict__ cntArr) {
  __shared__ unsigned short As[128 * 32];
  __shared__ unsigned short Bs[128 * 32];
  const int t = threadIdx.x, l = t & 63, w = t >> 6;
  const int wr = w >> 1, wc = w & 1;
  const int lq = l & 15, lh = l >> 4;

  const int nwg = (int)gridDim.x;
  const int flat = (int)blockIdx.x;
  const int q8 = nwg >> 3, r8 = nwg & 7, xcd = flat & 7;
  const int wgid = (xcd < r8 ? xcd * (q8 + 1) : r8 * (q8 + 1) + (xcd - r8) * q8) + (flat >> 3);
  const int pt = mTiles * nTiles;
  const int zb = wgid / pt;
  const int rm = wgid - zb * pt;
  const int mi = rm / nTiles;
  const int m0 = mi * 128;
  const int n0 = (rm - mi * nTiles) * 128;

  const int cb = cntArr[zb];
  if (m0 >= cb) return;
  const int nkt = nktFixed;

  const unsigned short* A = Ap + (size_t)zb * aStride + (size_t)m0 * lda;
  const unsigned short* B = Bp + (size_t)n0 * ldb;

  const int srow0 = w * 16 + (l >> 2);
  const int sg0 = l & 3;

  f32x4 acc[4][4] = {};
  for (int kt = 0; kt < nkt; ++kt) {
    const int d0 = kt * 32;
    __syncthreads();
#pragma unroll
    for (int p = 0; p < 2; ++p) {
      const int row = p * 64 + srow0;
      const int sg = sg0 ^ ((row >> 1) & 3);
      gload_lds16(A + (size_t)row * lda + d0 + sg * 8,
                  (char*)As + (size_t)(p * 64 + w * 16) * 64);
      gload_lds16(B + (size_t)row * ldb + d0 + sg * 8,
                  (char*)Bs + (size_t)(p * 64 + w * 16) * 64);
    }
    __syncthreads();
    bf16x8 aF[4], bF[4];
#pragma unroll
    for (int i = 0; i < 4; ++i) {
      const int rowA = 64 * wr + 16 * i + lq;
      aF[i] = *(const bf16x8*)(As + (size_t)rowA * 32 +
                               (size_t)(lh ^ ((rowA >> 1) & 3)) * 8);
      const int rowB = 64 * wc + 16 * i + lq;
      bF[i] = *(const bf16x8*)(Bs + (size_t)rowB * 32 +
                               (size_t)(lh ^ ((rowB >> 1) & 3)) * 8);
    }
#pragma unroll
    for (int i = 0; i < 4; ++i)
#pragma unroll
      for (int j = 0; j < 4; ++j) acc[i][j] = MFMA16(aF[i], bF[j], acc[i][j]);
  }

  // epilogue: C/D layout col = lane&15, row = (lane>>4)*4 + reg
#pragma unroll
  for (int j = 0; j < 4; ++j) {
    const int col = n0 + 64 * wc + 16 * j + lq;
    if (col >= ncols) continue;
    const int seg = (col >= 1920) ? 2 : (col >= 960 ? 1 : 0);
    const int dcol = col - seg * 960;
    const float bv = bias[col];
    if (seg == 2) {  // V: rows r=0..3 consecutive in Vt -> one u16x4
#pragma unroll
      for (int i = 0; i < 4; ++i) {
        const int row = m0 + 64 * wr + 16 * i + 4 * lh;
        u16x4 v4;
        v4[0] = f2bf(acc[i][j][0] + bv);
        v4[1] = f2bf(acc[i][j][1] + bv);
        v4[2] = f2bf(acc[i][j][2] + bv);
        v4[3] = f2bf(acc[i][j][3] + bv);
        *(u16x4*)(outV + ((size_t)zb << 20) + ((size_t)dcol << 10) + row) = v4;
      }
    } else {
#pragma unroll
      for (int i = 0; i < 4; ++i)
#pragma unroll
        for (int r = 0; r < 4; ++r) {
          const int row = m0 + 64 * wr + 16 * i + 4 * lh + r;
          const unsigned short v = f2bf(acc[i][j][r] + bv);
          if (seg == 0) outQ[((size_t)zb * 1024 + row) * 960 + dcol] = v;
          else outK[((size_t)zb * 1024 + row) * 960 + dcol] = v;
        }
    }
  }
}

// ---------------------------------------------------------------------------
// attn_fused<NKS>: scores + masked softmax + PV, fully fused.
// Bracket: NKS=4 handles nks<=4; NKS=6 handles 5..6; NKS=8 handles 7..8.
// QK phase: K slabs (NKS strips, dead strips dummy-staged) + Q, dbuf,
//   counted vmcnt(NKS+1); wave w computes k-strip w (gated w<nks).
// P phase: normalized P written bf16 into LDS over the dead Ks buffers,
//   [64][NKS*128], 16B-slot XOR swizzle by (row&7).
// PV phase: waves own 128 d-cols; A-frags from P-LDS (ds_read_b128),
//   B-frags direct 16B global reads from Vt (L2/L3); no barriers in loop.
// ctx written over Qb (identical addressing; block writes only its own rows).
// ---------------------------------------------------------------------------
template <int NKS>
__global__ __launch_bounds__(512) void attn_fused(
    const unsigned short* __restrict__ Qb, const unsigned short* __restrict__ Kb,
    const unsigned short* __restrict__ Vt, const int* __restrict__ cnt,
    unsigned short* __restrict__ ctxb) {
  __shared__ unsigned short Ks[2][NKS * 128 * 32];
  __shared__ unsigned short Qs[2][64 * 32];
  __shared__ float red[2][8][64];
  const int t = threadIdx.x, l = t & 63, w = t >> 6;
  const int flat = blockIdx.x;
  const int b = (flat & 7) * 4 + ((flat >> 3) >> 4);
  const int q0 = ((flat >> 3) & 15) * 64;
  const int cb = cnt[b];
  if (q0 >= cb) return;
  const int nks = (cb + 127) >> 7;
  if constexpr (NKS == 4) { if (nks > 4) return; }
  else if constexpr (NKS == 6) { if (nks <= 4 || nks > 6) return; }
  else { if (nks <= 6) return; }
  const int lq = l & 15, lh = l >> 4;
  const unsigned short* Kp = Kb + (size_t)b * 1024 * 960;
  const unsigned short* Qp = Qb + ((size_t)b * 1024 + q0) * 960;
  const int lr = l >> 2, sg0 = l & 3;

#define STG(kkv, bufv)                                                        \
  {                                                                           \
    const int d0_ = (kkv) * 32;                                               \
    _Pragma("unroll") for (int i_ = 0; i_ < NKS; ++i_) {                      \
      const int br_ = i_ * 128 + w * 16;                                      \
      const int kr_ = (i_ < nks) ? (br_ + lr) : (w * 16 + lr);                \
      const int sg_ = sg0 ^ ((kr_ >> 1) & 3);                                 \
      gload_lds16(Kp + (size_t)kr_ * 960 + d0_ + sg_ * 8,                     \
                  (char*)Ks[(bufv)] + (size_t)br_ * 64);                      \
    }                                                                         \
    {                                                                         \
      const int qw_ = w & 3;                                                  \
      const int qr_ = qw_ * 16 + lr;                                          \
      const int sg_ = sg0 ^ ((qr_ >> 1) & 3);                                 \
      gload_lds16(Qp + (size_t)qr_ * 960 + d0_ + sg_ * 8,                     \
                  (char*)Qs[(bufv)] + (size_t)(qw_ * 16) * 64);               \
    }                                                                         \
  }

  f32x4 acc[4][8] = {};
  STG(0, 0);
  int buf = 0;
  for (int kk = 0; kk < 30; ++kk) {
    if (kk < 29) {
      STG(kk + 1, buf ^ 1);
      if constexpr (NKS == 4)      asm volatile("s_waitcnt vmcnt(5)" ::: "memory");
      else if constexpr (NKS == 6) asm volatile("s_waitcnt vmcnt(7)" ::: "memory");
      else                         asm volatile("s_waitcnt vmcnt(9)" ::: "memory");
    } else {
      asm volatile("s_waitcnt vmcnt(0)" ::: "memory");
    }
    __builtin_amdgcn_sched_barrier(0);
    __builtin_amdgcn_s_barrier();
    if (w < nks) {
      bf16x8 aF[4], bF[8];
#pragma unroll
      for (int i = 0; i < 4; ++i) {
        const int qr = 16 * i + lq;
        aF[i] = *(const bf16x8*)(Qs[buf] + qr * 32 + (lh ^ ((qr >> 1) & 3)) * 8);
      }
#pragma unroll
      for (int j = 0; j < 8; ++j) {
        const int kr = 128 * w + 16 * j + lq;
        bF[j] = *(const bf16x8*)(Ks[buf] + kr * 32 + (lh ^ ((kr >> 1) & 3)) * 8);
      }
#pragma unroll
      for (int i = 0; i < 4; ++i)
#pragma unroll
        for (int j = 0; j < 8; ++j) acc[i][j] = MFMA16(aF[i], bF[j], acc[i][j]);
    }
    __builtin_amdgcn_s_barrier();
    buf ^= 1;
  }
#undef STG

  // cols >= cnt -> -1e9 (exp -> exact 0); covers dead waves (acc was 0)
#pragma unroll
  for (int j = 0; j < 8; ++j) {
    const int k = 128 * w + 16 * j + lq;
    if (k >= cb) {
#pragma unroll
      for (int i = 0; i < 4; ++i)
#pragma unroll
        for (int r = 0; r < 4; ++r) acc[i][j][r] = -1e9f;
    }
  }

  float rmax[4][4];
#pragma unroll
  for (int i = 0; i < 4; ++i)
#pragma unroll
    for (int r = 0; r < 4; ++r) {
      float m = acc[i][0][r];
#pragma unroll
      for (int j = 1; j < 8; ++j) m = fmaxf(m, acc[i][j][r]);
      m = fmaxf(m, __shfl_xor(m, 1));
      m = fmaxf(m, __shfl_xor(m, 2));
      m = fmaxf(m, __shfl_xor(m, 4));
      m = fmaxf(m, __shfl_xor(m, 8));
      rmax[i][r] = m;
    }
  if (lq == 0) {
#pragma unroll
    for (int i = 0; i < 4; ++i)
#pragma unroll
      for (int r = 0; r < 4; ++r) red[0][w][16 * i + 4 * lh + r] = rmax[i][r];
  }
  __syncthreads();
#pragma unroll
  for (int i = 0; i < 4; ++i)
#pragma unroll
    for (int r = 0; r < 4; ++r) {
      const int rowi = 16 * i + 4 * lh + r;
      float m = red[0][0][rowi];
#pragma unroll
      for (int w2 = 1; w2 < 8; ++w2) m = fmaxf(m, red[0][w2][rowi]);
      rmax[i][r] = m;
    }

  float rsum[4][4];
#pragma unroll
  for (int i = 0; i < 4; ++i)
#pragma unroll
    for (int r = 0; r < 4; ++r) {
      float s = 0.f;
#pragma unroll
      for (int j = 0; j < 8; ++j) {
        const float e = __expf(acc[i][j][r] - rmax[i][r]);
        acc[i][j][r] = e;
        s += e;
      }
      s += __shfl_xor(s, 1); s += __shfl_xor(s, 2);
      s += __shfl_xor(s, 4); s += __shfl_xor(s, 8);
      rsum[i][r] = s;
    }
  if (lq == 0) {
#pragma unroll
    for (int i = 0; i < 4; ++i)
#pragma unroll
      for (int r = 0; r < 4; ++r) red[1][w][16 * i + 4 * lh + r] = rsum[i][r];
  }
  __syncthreads();  // also: all QK reads of Ks done -> safe to overlay P

  // ---- P phase: write normalized P bf16 into LDS over Ks ----
  unsigned short* Ps = &Ks[0][0];
  constexpr int PW = NKS * 128;
  if (w < NKS) {  // dead strips (w in [nks,NKS)) write exact zeros
#pragma unroll
    for (int i = 0; i < 4; ++i)
#pragma unroll
      for (int r = 0; r < 4; ++r) {
        const int rowi = 16 * i + 4 * lh + r;
        float s = 0.f;
#pragma unroll
        for (int w2 = 0; w2 < 8; ++w2) s += red[1][w2][rowi];
        const float inv = 1.0f / s;
#pragma unroll
        for (int j = 0; j < 8; ++j) {
          const int col = 128 * w + 16 * j + lq;
          const int sw = ((col >> 3) ^ (rowi & 7)) * 8 + (col & 7);
          Ps[rowi * PW + sw] = f2bf(acc[i][j][r] * inv);
        }
      }
  }
  __syncthreads();

  // ---- PV phase: waves own d-columns; no barriers in loop ----
  const int nkt2 = (cb + 31) >> 5;
  const int d0w = w * 128;
  const int jmax = (d0w + 128 <= 960) ? 8 : 4;  // wave 7: d 896..959
  const unsigned short* Vb = Vt + ((size_t)b << 20);
  f32x4 acc2[4][8] = {};
  for (int kt = 0; kt < nkt2; ++kt) {
    bf16x8 aF[4];
#pragma unroll
    for (int i = 0; i < 4; ++i) {
      const int q = 16 * i + lq;
      const int slot = (kt * 4 + lh) ^ (q & 7);
      aF[i] = *(const bf16x8*)(Ps + q * PW + slot * 8);
    }
    for (int j = 0; j < jmax; ++j) {
      const int d = d0w + 16 * j + lq;
      const bf16x8 bF = *(const bf16x8*)(Vb + (size_t)d * 1024 + kt * 32 + lh * 8);
#pragma unroll
      for (int i = 0; i < 4; ++i) acc2[i][j] = MFMA16(aF[i], bF, acc2[i][j]);
    }
  }

  // ctx write (over Qb rows [q0,q0+64) — only this block read them as Q)
  for (int j = 0; j < jmax; ++j) {
    const int d = d0w + 16 * j + lq;
#pragma unroll
    for (int i = 0; i < 4; ++i)
#pragma unroll
      for (int r = 0; r < 4; ++r) {
        const int row = q0 + 16 * i + 4 * lh + r;
        ctxb[((size_t)b * 1024 + row) * 960 + d] = f2bf(acc2[i][j][r]);
      }
  }
}

// ---------------------------------------------------------------------------
// Compacted LN+pool.
// ---------------------------------------------------------------------------
__global__ __launch_bounds__(256) void ln_pool(
    const unsigned short* __restrict__ ctxb, const float* __restrict__ x,
    const int* __restrict__ idx, const int* __restrict__ cnt,
    const float* __restrict__ g, const float* __restrict__ bta,
    float* __restrict__ pooled) {
  const int b = blockIdx.y, chunk = blockIdx.x;
  const int w = threadIdx.x >> 6, l = threadIdx.x & 63;
  const int cb = cnt[b];
  f32x4 gc[4], bc[4];
#pragma unroll
  for (int c = 0; c < 4; ++c) {
    const int i4 = c * 64 + l;
    if (i4 < 240) {
      gc[c] = *(const f32x4*)(g + i4 * 4);
      bc[c] = *(const f32x4*)(bta + i4 * 4);
    }
  }
  f32x4 accp[4] = {};
  for (int rr = 0; rr < 8; ++rr) {
    const int j = chunk * 32 + w * 8 + rr;
    if (j >= cb) continue;
    const int sidx = idx[b * 1024 + j];
    const size_t cbase = ((size_t)b * 1024 + j) * 960;
    const size_t xbase = ((size_t)b * 1024 + sidx) * 960;
    f32x4 h[4];
    float part = 0.f;
#pragma unroll
    for (int c = 0; c < 4; ++c) {
      const int i4 = c * 64 + l;
      if (i4 < 240) {
        u16x4 cv = *(const u16x4*)(ctxb + cbase + (size_t)i4 * 4);
        f32x4 xv = *(const f32x4*)(x + xbase + (size_t)i4 * 4);
        h[c][0] = bf2f(cv[0]) + xv[0];
        h[c][1] = bf2f(cv[1]) + xv[1];
        h[c][2] = bf2f(cv[2]) + xv[2];
        h[c][3] = bf2f(cv[3]) + xv[3];
        part += h[c][0] + h[c][1] + h[c][2] + h[c][3];
      } else {
        h[c] = 0;
      }
    }
#pragma unroll
    for (int o = 1; o < 64; o <<= 1) part += __shfl_xor(part, o);
    const float mu = part * (1.0f / 960.0f);
    float p2 = 0.f;
#pragma unroll
    for (int c = 0; c < 4; ++c) {
      if (c * 64 + l < 240) {
#pragma unroll
        for (int k2 = 0; k2 < 4; ++k2) {
          const float d = h[c][k2] - mu;
          p2 += d * d;
        }
      }
    }
#pragma unroll
    for (int o = 1; o < 64; o <<= 1) p2 += __shfl_xor(p2, o);
    const float rs = rsqrtf(p2 * (1.0f / 960.0f) + 1e-5f);
#pragma unroll
    for (int c = 0; c < 4; ++c) {
      if (c * 64 + l < 240) {
#pragma unroll
        for (int k2 = 0; k2 < 4; ++k2)
          accp[c][k2] += (h[c][k2] - mu) * rs * gc[c][k2] + bc[c][k2];
      }
    }
  }
#pragma unroll
  for (int c = 0; c < 4; ++c) {
    const int i4 = c * 64 + l;
    if (i4 < 240) {
#pragma unroll
      for (int k2 = 0; k2 < 4; ++k2) atomicAdd(&pooled[b * 960 + i4 * 4 + k2], accp[c][k2]);
    }
  }
}

// ---------------------------------------------------------------------------
// pooled/cnt -> 960-512-256-128-10 MLP fp32.
// ---------------------------------------------------------------------------
__global__ __launch_bounds__(256) void mlp_head(
    const float* __restrict__ pooled, const int* __restrict__ cnt,
    const float* __restrict__ W1, const float* __restrict__ b1,
    const float* __restrict__ W2, const float* __restrict__ b2,
    const float* __restrict__ W3, const float* __restrict__ b3,
    const float* __restrict__ W4, const float* __restrict__ b4, float* __restrict__ out) {
  __shared__ float h0[960], h1[512], h2[256], h3[128];
  const int b = blockIdx.x, t = threadIdx.x;
  const float inv = 1.0f / fmaxf((float)cnt[b], 1e-9f);
  for (int d = t; d < 960; d += 256) h0[d] = pooled[b * 960 + d] * inv;
  __syncthreads();
  for (int o = t; o < 512; o += 256) {
    float a = b1[o];
    const float* wr = W1 + (size_t)o * 960;
    for (int k = 0; k < 960; k += 4) {
      f32x4 wv = *(const f32x4*)(wr + k);
      f32x4 hv = *(const f32x4*)(h0 + k);
      a += wv[0] * hv[0] + wv[1] * hv[1] + wv[2] * hv[2] + wv[3] * hv[3];
    }
    h1[o] = fmaxf(a, 0.f);
  }
  __syncthreads();
  {
    float a = b2[t];
    const float* wr = W2 + (size_t)t * 512;
    for (int k = 0; k < 512; k += 4) {
      f32x4 wv = *(const f32x4*)(wr + k);
      f32x4 hv = *(const f32x4*)(h1 + k);
      a += wv[0] * hv[0] + wv[1] * hv[1] + wv[2] * hv[2] + wv[3] * hv[3];
    }
    h2[t] = fmaxf(a, 0.f);
  }
  __syncthreads();
  if (t < 128) {
    float a = b3[t];
    const float* wr = W3 + (size_t)t * 256;
    for (int k = 0; k < 256; k += 4) {
      f32x4 wv = *(const f32x4*)(wr + k);
      f32x4 hv = *(const f32x4*)(h2 + k);
      a += wv[0] * hv[0] + wv[1] * hv[1] + wv[2] * hv[2] + wv[3] * hv[3];
    }
    h3[t] = fmaxf(a, 0.f);
  }
  __syncthreads();
  if (t < 10) {
    float a = b4[t];
    const float* wr = W4 + (size_t)t * 128;
    for (int k = 0; k < 128; ++k) a += wr[k] * h3[k];
    out[b * 10 + t] = a;
  }
}

// ---------------------------------------------------------------------------
// Workspace (bytes) — same as rounds 8-11:
//   [0,          67108864)  xc bf16 [32][1024][1024]
//   [67108864,  130023424)  Qb bf16 [32][1024][960] -> ctx bf16 (in-place)
//   [130023424, 192937984)  Kb bf16 [32][1024][960]
//   [192937984, 260046848)  Vt bf16 [32][1024][1024]
//   [260046848, 266338304)  Wqkv bf16 [3072][1024]
//   [266338304, 266349824)  biasQKV f32 [2880]
//   [266349824, 266472704)  pooled f32 [32][960]
//   [266472704, 266472832)  cnt i32 [32]
//   [266472832, 266603904)  idx i32 [32][1024]
// ---------------------------------------------------------------------------
extern "C" void kernel_launch(void* const* d_in, const int* in_sizes, int n_in,
                              void* d_out, int out_size, void* d_ws, size_t ws_size,
                              hipStream_t stream) {
  (void)in_sizes; (void)n_in; (void)out_size; (void)ws_size;
  const float* x    = (const float*)d_in[0];
  const int*   mask = (const int*)d_in[1];
  const float* Wq   = (const float*)d_in[2];
  const float* bq   = (const float*)d_in[3];
  const float* Wk   = (const float*)d_in[4];
  const float* bk   = (const float*)d_in[5];
  const float* Wv   = (const float*)d_in[6];
  const float* bv   = (const float*)d_in[7];
  const float* lng  = (const float*)d_in[8];
  const float* lnb  = (const float*)d_in[9];
  const float* W1   = (const float*)d_in[10];
  const float* b1   = (const float*)d_in[11];
  const float* W2   = (const float*)d_in[12];
  const float* b2   = (const float*)d_in[13];
  const float* W3   = (const float*)d_in[14];
  const float* b3   = (const float*)d_in[15];
  const float* W4   = (const float*)d_in[16];
  const float* b4   = (const float*)d_in[17];
  float* out = (float*)d_out;

  char* ws = (char*)d_ws;
  unsigned short* xc     = (unsigned short*)(ws);
  unsigned short* Qb     = (unsigned short*)(ws + 67108864);
  unsigned short* Kb     = (unsigned short*)(ws + 130023424);
  unsigned short* ctxb   = (unsigned short*)(ws + 67108864);  // in-place over Qb
  unsigned short* Vt     = (unsigned short*)(ws + 192937984);
  unsigned short* Wqkv   = (unsigned short*)(ws + 260046848);
  float*          biasQ  = (float*)(ws + 266338304);
  float*          pooled = (float*)(ws + 266349824);
  int*            cntW   = (int*)(ws + 266472704);
  int*            idxW   = (int*)(ws + 266472832);

  const float scaleQ = 0.0322748612183951f;  // 1/sqrt(960)

  scan_mask<<<32, 256, 0, stream>>>(mask, idxW, cntW);
  cast_wqkv<<<2880, 256, 0, stream>>>(Wq, Wk, Wv, bq, bk, bv, Wqkv, biasQ, scaleQ);
  compact_x<<<dim3(256, 32), 256, 0, stream>>>(x, idxW, cntW, xc);

  // fused QKV: per b, M = ceil128(cnt[b]) (early-exit), N = 2880, K = 960
  gemm128s<<<32 * 8 * 23, 256, 0, stream>>>(
      xc, Wqkv, 1024, 1024, biasQ, Qb, Kb, Vt,
      8, 23, 30, 2880, (size_t)1048576, cntW);

  // fused attention (scores+softmax+PV); brackets by nks=ceil128(cnt)
  attn_fused<4><<<512, 512, 0, stream>>>(Qb, Kb, Vt, cntW, ctxb);
  attn_fused<6><<<512, 512, 0, stream>>>(Qb, Kb, Vt, cntW, ctxb);
  attn_fused<8><<<512, 512, 0, stream>>>(Qb, Kb, Vt, cntW, ctxb);

  hipMemsetAsync(pooled, 0, 32 * 960 * 4, stream);
  ln_pool<<<dim3(32, 32), 256, 0, stream>>>(ctxb, x, idxW, cntW, lng, lnb, pooled);
  mlp_head<<<32, 256, 0, stream>>>(pooled, cntW, W1, b1, W2, b2, W3, b3, W4, b4, out);
}

// Round 13
// 573.480 us; speedup vs baseline: 2.1541x; 2.1541x over previous
//
#include <hip/hip_runtime.h>

// ---------------------------------------------------------------------------
// DeepProteinClassifier, mask-compacted, attention fused end-to-end:
//   scan_mask -> compact_x -> QKV gemm -> attn_fused (scores+softmax+PV,
//   P kept in LDS, V read direct from L2/L3, ctx written in-place over Qb)
//   -> LN+pool -> MLP.
// R13 fix vs R12: PV loop statically unrolled (rule #20 — runtime-indexed
// ext_vector accumulator was spilling to scratch: 698MB writes, MfmaUtil 1.6%).
// ---------------------------------------------------------------------------

#define DEVINL __device__ __forceinline__

typedef __attribute__((ext_vector_type(8))) short bf16x8;
typedef __attribute__((ext_vector_type(4))) float f32x4;
typedef __attribute__((ext_vector_type(4))) unsigned short u16x4;

DEVINL unsigned short f2bf(float f) {
  unsigned int u = __float_as_uint(f);
  u += 0x7FFFu + ((u >> 16) & 1u);  // round-to-nearest-even
  return (unsigned short)(u >> 16);
}

DEVINL float bf2f(unsigned short h) { return __uint_as_float(((unsigned int)h) << 16); }

DEVINL void gload_lds16(const void* g, void* l) {
  __builtin_amdgcn_global_load_lds((const __attribute__((address_space(1))) unsigned int*)g,
                                   (__attribute__((address_space(3))) unsigned int*)l,
                                   16, 0, 0);
}

#define MFMA16(a, b, c) __builtin_amdgcn_mfma_f32_16x16x32_bf16((a), (b), (c), 0, 0, 0)

// ---------------------------------------------------------------------------
// Per-b prefix scan of mask: idx[b][j] = s of j-th unmasked row; cnt[b].
// ---------------------------------------------------------------------------
__global__ __launch_bounds__(256) void scan_mask(
    const int* __restrict__ mask, int* __restrict__ idx, int* __restrict__ cnt) {
  __shared__ int ps[256];
  const int b = blockIdx.x, t = threadIdx.x;
  const int4 m = *(const int4*)(mask + b * 1024 + t * 4);
  const int s = (m.x != 0) + (m.y != 0) + (m.z != 0) + (m.w != 0);
  ps[t] = s;
  __syncthreads();
  for (int off = 1; off < 256; off <<= 1) {
    const int v = (t >= off) ? ps[t - off] : 0;
    __syncthreads();
    ps[t] += v;
    __syncthreads();
  }
  int pos = ps[t] - s;
  if (m.x) idx[b * 1024 + pos++] = t * 4 + 0;
  if (m.y) idx[b * 1024 + pos++] = t * 4 + 1;
  if (m.z) idx[b * 1024 + pos++] = t * 4 + 2;
  if (m.w) idx[b * 1024 + pos++] = t * 4 + 3;
  if (t == 255) cnt[b] = ps[255];
}

// ---------------------------------------------------------------------------
// Build Wqkv [3072][1024] bf16 + biasQKV[2880] f32 (Q pre-scaled).
// ---------------------------------------------------------------------------
__global__ __launch_bounds__(256) void cast_wqkv(
    const float* __restrict__ Wq, const float* __restrict__ Wk, const float* __restrict__ Wv,
    const float* __restrict__ bq, const float* __restrict__ bk, const float* __restrict__ bv,
    unsigned short* __restrict__ Wqkv, float* __restrict__ biasQ, float scaleQ) {
  const int r = blockIdx.x, t = threadIdx.x;
  const int seg = (r >= 1920) ? 2 : (r >= 960 ? 1 : 0);
  const int sr = r - seg * 960;
  const float* W = (seg == 0) ? Wq : (seg == 1) ? Wk : Wv;
  const float sc = (seg == 0) ? scaleQ : 1.0f;
  if (t < 240) {
    f32x4 v = *(const f32x4*)(W + (size_t)sr * 960 + t * 4);
    u16x4 o;
    o[0] = f2bf(v[0] * sc); o[1] = f2bf(v[1] * sc);
    o[2] = f2bf(v[2] * sc); o[3] = f2bf(v[3] * sc);
    *(u16x4*)(Wqkv + (size_t)r * 1024 + t * 4) = o;
  } else {
    u16x4 z = {};
    *(u16x4*)(Wqkv + (size_t)r * 1024 + 960 + (t - 240) * 4) = z;
  }
  if (t == 0) {
    const float* bb = (seg == 0) ? bq : (seg == 1) ? bk : bv;
    biasQ[r] = bb[sr] * sc;
  }
}

// ---------------------------------------------------------------------------
// Gather-compact-cast: xc[b][j] = bf16(x[b][idx[b][j]]) for j < cnt[b];
// zero rows j in [cnt, ceil128(cnt)); 1024 cols (960 data + 64 zero pad).
// ---------------------------------------------------------------------------
__global__ __launch_bounds__(256) void compact_x(
    const float* __restrict__ x, const int* __restrict__ idx, const int* __restrict__ cnt,
    unsigned short* __restrict__ xc) {
  const int b = blockIdx.y;
  const int j = blockIdx.x * 4 + (threadIdx.x >> 6);
  const int l = threadIdx.x & 63;
  const int cb = cnt[b];
  const int cbc = (cb + 127) & ~127;
  if (j >= cbc) return;
  unsigned short* o = xc + ((size_t)b * 1024 + j) * 1024 + l * 16;
  bf16x8 o0 = {}, o1 = {};
  if (j < cb && l < 60) {
    const int s = idx[b * 1024 + j];
    const float* g = x + ((size_t)b * 1024 + s) * 960 + l * 16;
    f32x4 v0 = *(const f32x4*)(g);
    f32x4 v1 = *(const f32x4*)(g + 4);
    f32x4 v2 = *(const f32x4*)(g + 8);
    f32x4 v3 = *(const f32x4*)(g + 12);
    o0[0] = (short)f2bf(v0[0]); o0[1] = (short)f2bf(v0[1]);
    o0[2] = (short)f2bf(v0[2]); o0[3] = (short)f2bf(v0[3]);
    o0[4] = (short)f2bf(v1[0]); o0[5] = (short)f2bf(v1[1]);
    o0[6] = (short)f2bf(v1[2]); o0[7] = (short)f2bf(v1[3]);
    o1[0] = (short)f2bf(v2[0]); o1[1] = (short)f2bf(v2[1]);
    o1[2] = (short)f2bf(v2[2]); o1[3] = (short)f2bf(v2[3]);
    o1[4] = (short)f2bf(v3[0]); o1[5] = (short)f2bf(v3[1]);
    o1[6] = (short)f2bf(v3[2]); o1[7] = (short)f2bf(v3[3]);
  }
  *(bf16x8*)(o) = o0;
  *(bf16x8*)(o + 8) = o1;
}

// ---------------------------------------------------------------------------
// gemm128s: 128x128 NT GEMM, m97 structure (BK=32, single 16KB LDS, 4 waves,
// plain __syncthreads). (row>>1)&3 slot swizzle. Per-b compaction via cntArr.
// QKV epilogue: bf16 +bias -> Qb/Kb/Vt-transposed (V-stores merged u16x4).
// ---------------------------------------------------------------------------
__global__ __launch_bounds__(256, 4) void gemm128s(
    const unsigned short* __restrict__ Ap, const unsigned short* __restrict__ Bp,
    int lda, int ldb, const float* __restrict__ bias,
    unsigned short* __restrict__ outQ, unsigned short* __restrict__ outK,
    unsigned short* __restrict__ outV,
    int mTiles, int nTiles, int nktFixed, int ncols,
    size_t aStride, const int* __restrict__ cntArr) {
  __shared__ unsigned short As[128 * 32];
  __shared__ unsigned short Bs[128 * 32];
  const int t = threadIdx.x, l = t & 63, w = t >> 6;
  const int wr = w >> 1, wc = w & 1;
  const int lq = l & 15, lh = l >> 4;

  const int nwg = (int)gridDim.x;
  const int flat = (int)blockIdx.x;
  const int q8 = nwg >> 3, r8 = nwg & 7, xcd = flat & 7;
  const int wgid = (xcd < r8 ? xcd * (q8 + 1) : r8 * (q8 + 1) + (xcd - r8) * q8) + (flat >> 3);
  const int pt = mTiles * nTiles;
  const int zb = wgid / pt;
  const int rm = wgid - zb * pt;
  const int mi = rm / nTiles;
  const int m0 = mi * 128;
  const int n0 = (rm - mi * nTiles) * 128;

  const int cb = cntArr[zb];
  if (m0 >= cb) return;
  const int nkt = nktFixed;

  const unsigned short* A = Ap + (size_t)zb * aStride + (size_t)m0 * lda;
  const unsigned short* B = Bp + (size_t)n0 * ldb;

  const int srow0 = w * 16 + (l >> 2);
  const int sg0 = l & 3;

  f32x4 acc[4][4] = {};
  for (int kt = 0; kt < nkt; ++kt) {
    const int d0 = kt * 32;
    __syncthreads();
#pragma unroll
    for (int p = 0; p < 2; ++p) {
      const int row = p * 64 + srow0;
      const int sg = sg0 ^ ((row >> 1) & 3);
      gload_lds16(A + (size_t)row * lda + d0 + sg * 8,
                  (char*)As + (size_t)(p * 64 + w * 16) * 64);
      gload_lds16(B + (size_t)row * ldb + d0 + sg * 8,
                  (char*)Bs + (size_t)(p * 64 + w * 16) * 64);
    }
    __syncthreads();
    bf16x8 aF[4], bF[4];
#pragma unroll
    for (int i = 0; i < 4; ++i) {
      const int rowA = 64 * wr + 16 * i + lq;
      aF[i] = *(const bf16x8*)(As + (size_t)rowA * 32 +
                               (size_t)(lh ^ ((rowA >> 1) & 3)) * 8);
      const int rowB = 64 * wc + 16 * i + lq;
      bF[i] = *(const bf16x8*)(Bs + (size_t)rowB * 32 +
                               (size_t)(lh ^ ((rowB >> 1) & 3)) * 8);
    }
#pragma unroll
    for (int i = 0; i < 4; ++i)
#pragma unroll
      for (int j = 0; j < 4; ++j) acc[i][j] = MFMA16(aF[i], bF[j], acc[i][j]);
  }

  // epilogue: C/D layout col = lane&15, row = (lane>>4)*4 + reg
#pragma unroll
  for (int j = 0; j < 4; ++j) {
    const int col = n0 + 64 * wc + 16 * j + lq;
    if (col >= ncols) continue;
    const int seg = (col >= 1920) ? 2 : (col >= 960 ? 1 : 0);
    const int dcol = col - seg * 960;
    const float bv = bias[col];
    if (seg == 2) {  // V: rows r=0..3 consecutive in Vt -> one u16x4
#pragma unroll
      for (int i = 0; i < 4; ++i) {
        const int row = m0 + 64 * wr + 16 * i + 4 * lh;
        u16x4 v4;
        v4[0] = f2bf(acc[i][j][0] + bv);
        v4[1] = f2bf(acc[i][j][1] + bv);
        v4[2] = f2bf(acc[i][j][2] + bv);
        v4[3] = f2bf(acc[i][j][3] + bv);
        *(u16x4*)(outV + ((size_t)zb << 20) + ((size_t)dcol << 10) + row) = v4;
      }
    } else {
#pragma unroll
      for (int i = 0; i < 4; ++i)
#pragma unroll
        for (int r = 0; r < 4; ++r) {
          const int row = m0 + 64 * wr + 16 * i + 4 * lh + r;
          const unsigned short v = f2bf(acc[i][j][r] + bv);
          if (seg == 0) outQ[((size_t)zb * 1024 + row) * 960 + dcol] = v;
          else outK[((size_t)zb * 1024 + row) * 960 + dcol] = v;
        }
    }
  }
}

// ---------------------------------------------------------------------------
// attn_fused<NKS>: scores + masked softmax + PV, fully fused.
// Bracket: NKS=4 handles nks<=4; NKS=6 handles 5..6; NKS=8 handles 7..8.
// QK phase: K slabs (NKS strips, dead strips dummy-staged) + Q, dbuf,
//   counted vmcnt(NKS+1); wave w computes k-strip w (gated w<nks).
// P phase: normalized P bf16 in LDS over dead Ks, [64][NKS*128], XOR swizzle.
// PV phase: waves own 128 d-cols; A-frags ds_read from P-LDS; B-frags direct
//   16B global reads from Vt (L2/L3); STATIC j unroll (acc2 in registers).
// ctx written over Qb (identical addressing; block writes only its own rows).
// ---------------------------------------------------------------------------
template <int NKS>
__global__ __launch_bounds__(512) void attn_fused(
    const unsigned short* __restrict__ Qb, const unsigned short* __restrict__ Kb,
    const unsigned short* __restrict__ Vt, const int* __restrict__ cnt,
    unsigned short* __restrict__ ctxb) {
  __shared__ unsigned short Ks[2][NKS * 128 * 32];
  __shared__ unsigned short Qs[2][64 * 32];
  __shared__ float red[2][8][64];
  const int t = threadIdx.x, l = t & 63, w = t >> 6;
  const int flat = blockIdx.x;
  const int b = (flat & 7) * 4 + ((flat >> 3) >> 4);
  const int q0 = ((flat >> 3) & 15) * 64;
  const int cb = cnt[b];
  if (q0 >= cb) return;
  const int nks = (cb + 127) >> 7;
  if constexpr (NKS == 4) { if (nks > 4) return; }
  else if constexpr (NKS == 6) { if (nks <= 4 || nks > 6) return; }
  else { if (nks <= 6) return; }
  const int lq = l & 15, lh = l >> 4;
  const unsigned short* Kp = Kb + (size_t)b * 1024 * 960;
  const unsigned short* Qp = Qb + ((size_t)b * 1024 + q0) * 960;
  const int lr = l >> 2, sg0 = l & 3;

#define STG(kkv, bufv)                                                        \
  {                                                                           \
    const int d0_ = (kkv) * 32;                                               \
    _Pragma("unroll") for (int i_ = 0; i_ < NKS; ++i_) {                      \
      const int br_ = i_ * 128 + w * 16;                                      \
      const int kr_ = (i_ < nks) ? (br_ + lr) : (w * 16 + lr);                \
      const int sg_ = sg0 ^ ((kr_ >> 1) & 3);                                 \
      gload_lds16(Kp + (size_t)kr_ * 960 + d0_ + sg_ * 8,                     \
                  (char*)Ks[(bufv)] + (size_t)br_ * 64);                      \
    }                                                                         \
    {                                                                         \
      const int qw_ = w & 3;                                                  \
      const int qr_ = qw_ * 16 + lr;                                          \
      const int sg_ = sg0 ^ ((qr_ >> 1) & 3);                                 \
      gload_lds16(Qp + (size_t)qr_ * 960 + d0_ + sg_ * 8,                     \
                  (char*)Qs[(bufv)] + (size_t)(qw_ * 16) * 64);               \
    }                                                                         \
  }

  f32x4 acc[4][8] = {};
  STG(0, 0);
  int buf = 0;
  for (int kk = 0; kk < 30; ++kk) {
    if (kk < 29) {
      STG(kk + 1, buf ^ 1);
      if constexpr (NKS == 4)      asm volatile("s_waitcnt vmcnt(5)" ::: "memory");
      else if constexpr (NKS == 6) asm volatile("s_waitcnt vmcnt(7)" ::: "memory");
      else                         asm volatile("s_waitcnt vmcnt(9)" ::: "memory");
    } else {
      asm volatile("s_waitcnt vmcnt(0)" ::: "memory");
    }
    __builtin_amdgcn_sched_barrier(0);
    __builtin_amdgcn_s_barrier();
    if (w < nks) {
      bf16x8 aF[4], bF[8];
#pragma unroll
      for (int i = 0; i < 4; ++i) {
        const int qr = 16 * i + lq;
        aF[i] = *(const bf16x8*)(Qs[buf] + qr * 32 + (lh ^ ((qr >> 1) & 3)) * 8);
      }
#pragma unroll
      for (int j = 0; j < 8; ++j) {
        const int kr = 128 * w + 16 * j + lq;
        bF[j] = *(const bf16x8*)(Ks[buf] + kr * 32 + (lh ^ ((kr >> 1) & 3)) * 8);
      }
#pragma unroll
      for (int i = 0; i < 4; ++i)
#pragma unroll
        for (int j = 0; j < 8; ++j) acc[i][j] = MFMA16(aF[i], bF[j], acc[i][j]);
    }
    __builtin_amdgcn_s_barrier();
    buf ^= 1;
  }
#undef STG

  // cols >= cnt -> -1e9 (exp -> exact 0); covers dead waves (acc was 0)
#pragma unroll
  for (int j = 0; j < 8; ++j) {
    const int k = 128 * w + 16 * j + lq;
    if (k >= cb) {
#pragma unroll
      for (int i = 0; i < 4; ++i)
#pragma unroll
        for (int r = 0; r < 4; ++r) acc[i][j][r] = -1e9f;
    }
  }

  float rmax[4][4];
#pragma unroll
  for (int i = 0; i < 4; ++i)
#pragma unroll
    for (int r = 0; r < 4; ++r) {
      float m = acc[i][0][r];
#pragma unroll
      for (int j = 1; j < 8; ++j) m = fmaxf(m, acc[i][j][r]);
      m = fmaxf(m, __shfl_xor(m, 1));
      m = fmaxf(m, __shfl_xor(m, 2));
      m = fmaxf(m, __shfl_xor(m, 4));
      m = fmaxf(m, __shfl_xor(m, 8));
      rmax[i][r] = m;
    }
  if (lq == 0) {
#pragma unroll
    for (int i = 0; i < 4; ++i)
#pragma unroll
      for (int r = 0; r < 4; ++r) red[0][w][16 * i + 4 * lh + r] = rmax[i][r];
  }
  __syncthreads();
#pragma unroll
  for (int i = 0; i < 4; ++i)
#pragma unroll
    for (int r = 0; r < 4; ++r) {
      const int rowi = 16 * i + 4 * lh + r;
      float m = red[0][0][rowi];
#pragma unroll
      for (int w2 = 1; w2 < 8; ++w2) m = fmaxf(m, red[0][w2][rowi]);
      rmax[i][r] = m;
    }

  float rsum[4][4];
#pragma unroll
  for (int i = 0; i < 4; ++i)
#pragma unroll
    for (int r = 0; r < 4; ++r) {
      float s = 0.f;
#pragma unroll
      for (int j = 0; j < 8; ++j) {
        const float e = __expf(acc[i][j][r] - rmax[i][r]);
        acc[i][j][r] = e;
        s += e;
      }
      s += __shfl_xor(s, 1); s += __shfl_xor(s, 2);
      s += __shfl_xor(s, 4); s += __shfl_xor(s, 8);
      rsum[i][r] = s;
    }
  if (lq == 0) {
#pragma unroll
    for (int i = 0; i < 4; ++i)
#pragma unroll
      for (int r = 0; r < 4; ++r) red[1][w][16 * i + 4 * lh + r] = rsum[i][r];
  }
  __syncthreads();  // all QK reads of Ks done -> safe to overlay P

  // ---- P phase: write normalized P bf16 into LDS over Ks ----
  unsigned short* Ps = &Ks[0][0];
  constexpr int PW = NKS * 128;
  if (w < NKS) {  // dead strips (w in [nks,NKS)) write exact zeros
#pragma unroll
    for (int i = 0; i < 4; ++i)
#pragma unroll
      for (int r = 0; r < 4; ++r) {
        const int rowi = 16 * i + 4 * lh + r;
        float s = 0.f;
#pragma unroll
        for (int w2 = 0; w2 < 8; ++w2) s += red[1][w2][rowi];
        const float inv = 1.0f / s;
#pragma unroll
        for (int j = 0; j < 8; ++j) {
          const int col = 128 * w + 16 * j + lq;
          const int sw = ((col >> 3) ^ (rowi & 7)) * 8 + (col & 7);
          Ps[rowi * PW + sw] = f2bf(acc[i][j][r] * inv);
        }
      }
  }
  __syncthreads();

  // ---- PV phase: waves own d-columns; STATIC unroll (acc2 in registers) ----
  const int nkt2 = (cb + 31) >> 5;
  const int d0w = w * 128;
  const unsigned short* Vb = Vt + ((size_t)b << 20);
  f32x4 acc2[4][8] = {};
  for (int kt = 0; kt < nkt2; ++kt) {
    bf16x8 aF[4];
#pragma unroll
    for (int i = 0; i < 4; ++i) {
      const int q = 16 * i + lq;
      const int slot = (kt * 4 + lh) ^ (q & 7);
      aF[i] = *(const bf16x8*)(Ps + q * PW + slot * 8);
    }
#pragma unroll
    for (int j = 0; j < 8; ++j) {  // wave 7, j>=4: d in [960,1024) — in-bounds
      const int d = d0w + 16 * j + lq;  //   garbage rows, results discarded
      const bf16x8 bF = *(const bf16x8*)(Vb + (size_t)d * 1024 + kt * 32 + lh * 8);
#pragma unroll
      for (int i = 0; i < 4; ++i) acc2[i][j] = MFMA16(aF[i], bF, acc2[i][j]);
    }
  }

  // ctx write (over Qb rows [q0,q0+64) — only this block read them as Q)
#pragma unroll
  for (int j = 0; j < 8; ++j) {
    const int d = d0w + 16 * j + lq;
    if (d < 960) {
#pragma unroll
      for (int i = 0; i < 4; ++i)
#pragma unroll
        for (int r = 0; r < 4; ++r) {
          const int row = q0 + 16 * i + 4 * lh + r;
          ctxb[((size_t)b * 1024 + row) * 960 + d] = f2bf(acc2[i][j][r]);
        }
    }
  }
}

// ---------------------------------------------------------------------------
// Compacted LN+pool.
// ---------------------------------------------------------------------------
__global__ __launch_bounds__(256) void ln_pool(
    const unsigned short* __restrict__ ctxb, const float* __restrict__ x,
    const int* __restrict__ idx, const int* __restrict__ cnt,
    const float* __restrict__ g, const float* __restrict__ bta,
    float* __restrict__ pooled) {
  const int b = blockIdx.y, chunk = blockIdx.x;
  const int w = threadIdx.x >> 6, l = threadIdx.x & 63;
  const int cb = cnt[b];
  f32x4 gc[4], bc[4];
#pragma unroll
  for (int c = 0; c < 4; ++c) {
    const int i4 = c * 64 + l;
    if (i4 < 240) {
      gc[c] = *(const f32x4*)(g + i4 * 4);
      bc[c] = *(const f32x4*)(bta + i4 * 4);
    }
  }
  f32x4 accp[4] = {};
  for (int rr = 0; rr < 8; ++rr) {
    const int j = chunk * 32 + w * 8 + rr;
    if (j >= cb) continue;
    const int sidx = idx[b * 1024 + j];
    const size_t cbase = ((size_t)b * 1024 + j) * 960;
    const size_t xbase = ((size_t)b * 1024 + sidx) * 960;
    f32x4 h[4];
    float part = 0.f;
#pragma unroll
    for (int c = 0; c < 4; ++c) {
      const int i4 = c * 64 + l;
      if (i4 < 240) {
        u16x4 cv = *(const u16x4*)(ctxb + cbase + (size_t)i4 * 4);
        f32x4 xv = *(const f32x4*)(x + xbase + (size_t)i4 * 4);
        h[c][0] = bf2f(cv[0]) + xv[0];
        h[c][1] = bf2f(cv[1]) + xv[1];
        h[c][2] = bf2f(cv[2]) + xv[2];
        h[c][3] = bf2f(cv[3]) + xv[3];
        part += h[c][0] + h[c][1] + h[c][2] + h[c][3];
      } else {
        h[c] = 0;
      }
    }
#pragma unroll
    for (int o = 1; o < 64; o <<= 1) part += __shfl_xor(part, o);
    const float mu = part * (1.0f / 960.0f);
    float p2 = 0.f;
#pragma unroll
    for (int c = 0; c < 4; ++c) {
      if (c * 64 + l < 240) {
#pragma unroll
        for (int k2 = 0; k2 < 4; ++k2) {
          const float d = h[c][k2] - mu;
          p2 += d * d;
        }
      }
    }
#pragma unroll
    for (int o = 1; o < 64; o <<= 1) p2 += __shfl_xor(p2, o);
    const float rs = rsqrtf(p2 * (1.0f / 960.0f) + 1e-5f);
#pragma unroll
    for (int c = 0; c < 4; ++c) {
      if (c * 64 + l < 240) {
#pragma unroll
        for (int k2 = 0; k2 < 4; ++k2)
          accp[c][k2] += (h[c][k2] - mu) * rs * gc[c][k2] + bc[c][k2];
      }
    }
  }
#pragma unroll
  for (int c = 0; c < 4; ++c) {
    const int i4 = c * 64 + l;
    if (i4 < 240) {
#pragma unroll
      for (int k2 = 0; k2 < 4; ++k2) atomicAdd(&pooled[b * 960 + i4 * 4 + k2], accp[c][k2]);
    }
  }
}

// ---------------------------------------------------------------------------
// pooled/cnt -> 960-512-256-128-10 MLP fp32.
// ---------------------------------------------------------------------------
__global__ __launch_bounds__(256) void mlp_head(
    const float* __restrict__ pooled, const int* __restrict__ cnt,
    const float* __restrict__ W1, const float* __restrict__ b1,
    const float* __restrict__ W2, const float* __restrict__ b2,
    const float* __restrict__ W3, const float* __restrict__ b3,
    const float* __restrict__ W4, const float* __restrict__ b4, float* __restrict__ out) {
  __shared__ float h0[960], h1[512], h2[256], h3[128];
  const int b = blockIdx.x, t = threadIdx.x;
  const float inv = 1.0f / fmaxf((float)cnt[b], 1e-9f);
  for (int d = t; d < 960; d += 256) h0[d] = pooled[b * 960 + d] * inv;
  __syncthreads();
  for (int o = t; o < 512; o += 256) {
    float a = b1[o];
    const float* wr = W1 + (size_t)o * 960;
    for (int k = 0; k < 960; k += 4) {
      f32x4 wv = *(const f32x4*)(wr + k);
      f32x4 hv = *(const f32x4*)(h0 + k);
      a += wv[0] * hv[0] + wv[1] * hv[1] + wv[2] * hv[2] + wv[3] * hv[3];
    }
    h1[o] = fmaxf(a, 0.f);
  }
  __syncthreads();
  {
    float a = b2[t];
    const float* wr = W2 + (size_t)t * 512;
    for (int k = 0; k < 512; k += 4) {
      f32x4 wv = *(const f32x4*)(wr + k);
      f32x4 hv = *(const f32x4*)(h1 + k);
      a += wv[0] * hv[0] + wv[1] * hv[1] + wv[2] * hv[2] + wv[3] * hv[3];
    }
    h2[t] = fmaxf(a, 0.f);
  }
  __syncthreads();
  if (t < 128) {
    float a = b3[t];
    const float* wr = W3 + (size_t)t * 256;
    for (int k = 0; k < 256; k += 4) {
      f32x4 wv = *(const f32x4*)(wr + k);
      f32x4 hv = *(const f32x4*)(h2 + k);
      a += wv[0] * hv[0] + wv[1] * hv[1] + wv[2] * hv[2] + wv[3] * hv[3];
    }
    h3[t] = fmaxf(a, 0.f);
  }
  __syncthreads();
  if (t < 10) {
    float a = b4[t];
    const float* wr = W4 + (size_t)t * 128;
    for (int k = 0; k < 128; ++k) a += wr[k] * h3[k];
    out[b * 10 + t] = a;
  }
}

// ---------------------------------------------------------------------------
// Workspace (bytes) — same as rounds 8-12:
//   [0,          67108864)  xc bf16 [32][1024][1024]
//   [67108864,  130023424)  Qb bf16 [32][1024][960] -> ctx bf16 (in-place)
//   [130023424, 192937984)  Kb bf16 [32][1024][960]
//   [192937984, 260046848)  Vt bf16 [32][1024][1024]
//   [260046848, 266338304)  Wqkv bf16 [3072][1024]
//   [266338304, 266349824)  biasQKV f32 [2880]
//   [266349824, 266472704)  pooled f32 [32][960]
//   [266472704, 266472832)  cnt i32 [32]
//   [266472832, 266603904)  idx i32 [32][1024]
// ---------------------------------------------------------------------------
extern "C" void kernel_launch(void* const* d_in, const int* in_sizes, int n_in,
                              void* d_out, int out_size, void* d_ws, size_t ws_size,
                              hipStream_t stream) {
  (void)in_sizes; (void)n_in; (void)out_size; (void)ws_size;
  const float* x    = (const float*)d_in[0];
  const int*   mask = (const int*)d_in[1];
  const float* Wq   = (const float*)d_in[2];
  const float* bq   = (const float*)d_in[3];
  const float* Wk   = (const float*)d_in[4];
  const float* bk   = (const float*)d_in[5];
  const float* Wv   = (const float*)d_in[6];
  const float* bv   = (const float*)d_in[7];
  const float* lng  = (const float*)d_in[8];
  const float* lnb  = (const float*)d_in[9];
  const float* W1   = (const float*)d_in[10];
  const float* b1   = (const float*)d_in[11];
  const float* W2   = (const float*)d_in[12];
  const float* b2   = (const float*)d_in[13];
  const float* W3   = (const float*)d_in[14];
  const float* b3   = (const float*)d_in[15];
  const float* W4   = (const float*)d_in[16];
  const float* b4   = (const float*)d_in[17];
  float* out = (float*)d_out;

  char* ws = (char*)d_ws;
  unsigned short* xc     = (unsigned short*)(ws);
  unsigned short* Qb     = (unsigned short*)(ws + 67108864);
  unsigned short* Kb     = (unsigned short*)(ws + 130023424);
  unsigned short* ctxb   = (unsigned short*)(ws + 67108864);  // in-place over Qb
  unsigned short* Vt     = (unsigned short*)(ws + 192937984);
  unsigned short* Wqkv   = (unsigned short*)(ws + 260046848);
  float*          biasQ  = (float*)(ws + 266338304);
  float*          pooled = (float*)(ws + 266349824);
  int*            cntW   = (int*)(ws + 266472704);
  int*            idxW   = (int*)(ws + 266472832);

  const float scaleQ = 0.0322748612183951f;  // 1/sqrt(960)

  scan_mask<<<32, 256, 0, stream>>>(mask, idxW, cntW);
  cast_wqkv<<<2880, 256, 0, stream>>>(Wq, Wk, Wv, bq, bk, bv, Wqkv, biasQ, scaleQ);
  compact_x<<<dim3(256, 32), 256, 0, stream>>>(x, idxW, cntW, xc);

  // fused QKV: per b, M = ceil128(cnt[b]) (early-exit), N = 2880, K = 960
  gemm128s<<<32 * 8 * 23, 256, 0, stream>>>(
      xc, Wqkv, 1024, 1024, biasQ, Qb, Kb, Vt,
      8, 23, 30, 2880, (size_t)1048576, cntW);

  // fused attention (scores+softmax+PV); brackets by nks=ceil128(cnt)
  attn_fused<4><<<512, 512, 0, stream>>>(Qb, Kb, Vt, cntW, ctxb);
  attn_fused<6><<<512, 512, 0, stream>>>(Qb, Kb, Vt, cntW, ctxb);
  attn_fused<8><<<512, 512, 0, stream>>>(Qb, Kb, Vt, cntW, ctxb);

  hipMemsetAsync(pooled, 0, 32 * 960 * 4, stream);
  ln_pool<<<dim3(32, 32), 256, 0, stream>>>(ctxb, x, idxW, cntW, lng, lnb, pooled);
  mlp_head<<<32, 256, 0, stream>>>(pooled, cntW, W1, b1, W2, b2, W3, b3, W4, b4, out);
}

// Round 14
// 460.725 us; speedup vs baseline: 2.6813x; 1.2447x over previous
//
#include <hip/hip_runtime.h>

// ---------------------------------------------------------------------------
// DeepProteinClassifier with mask-compaction + attn strip-skip (NKS-templated
// staging: only live k-strips are staged; vmcnt ledger per-template).
//   scan_mask -> compact_x -> QKV gemm -> attn -> PV gemm -> LN+pool -> MLP.
// GEMM: m97-structure gemm128s (BK=32, single 16KB LDS, ~8 blocks/CU TLP).
// [R14 = revert to the round-11 measured optimum (457us). The round-12/13
//  fused-attn experiment is abandoned: uncoalesced 2KB-stride V reads +
//  1 block/CU occupancy made it structurally slower.]
// ---------------------------------------------------------------------------

#define DEVINL __device__ __forceinline__

typedef __attribute__((ext_vector_type(8))) short bf16x8;
typedef __attribute__((ext_vector_type(4))) float f32x4;
typedef __attribute__((ext_vector_type(4))) unsigned short u16x4;

DEVINL unsigned short f2bf(float f) {
  unsigned int u = __float_as_uint(f);
  u += 0x7FFFu + ((u >> 16) & 1u);  // round-to-nearest-even
  return (unsigned short)(u >> 16);
}

DEVINL float bf2f(unsigned short h) { return __uint_as_float(((unsigned int)h) << 16); }

DEVINL void gload_lds16(const void* g, void* l) {
  __builtin_amdgcn_global_load_lds((const __attribute__((address_space(1))) unsigned int*)g,
                                   (__attribute__((address_space(3))) unsigned int*)l,
                                   16, 0, 0);
}

#define MFMA16(a, b, c) __builtin_amdgcn_mfma_f32_16x16x32_bf16((a), (b), (c), 0, 0, 0)

// ---------------------------------------------------------------------------
// Per-b prefix scan of mask: idx[b][j] = s of j-th unmasked row; cnt[b].
// ---------------------------------------------------------------------------
__global__ __launch_bounds__(256) void scan_mask(
    const int* __restrict__ mask, int* __restrict__ idx, int* __restrict__ cnt) {
  __shared__ int ps[256];
  const int b = blockIdx.x, t = threadIdx.x;
  const int4 m = *(const int4*)(mask + b * 1024 + t * 4);
  const int s = (m.x != 0) + (m.y != 0) + (m.z != 0) + (m.w != 0);
  ps[t] = s;
  __syncthreads();
  for (int off = 1; off < 256; off <<= 1) {
    const int v = (t >= off) ? ps[t - off] : 0;
    __syncthreads();
    ps[t] += v;
    __syncthreads();
  }
  int pos = ps[t] - s;
  if (m.x) idx[b * 1024 + pos++] = t * 4 + 0;
  if (m.y) idx[b * 1024 + pos++] = t * 4 + 1;
  if (m.z) idx[b * 1024 + pos++] = t * 4 + 2;
  if (m.w) idx[b * 1024 + pos++] = t * 4 + 3;
  if (t == 255) cnt[b] = ps[255];
}

// ---------------------------------------------------------------------------
// Build Wqkv [3072][1024] bf16 + biasQKV[2880] f32 (Q pre-scaled).
// ---------------------------------------------------------------------------
__global__ __launch_bounds__(256) void cast_wqkv(
    const float* __restrict__ Wq, const float* __restrict__ Wk, const float* __restrict__ Wv,
    const float* __restrict__ bq, const float* __restrict__ bk, const float* __restrict__ bv,
    unsigned short* __restrict__ Wqkv, float* __restrict__ biasQ, float scaleQ) {
  const int r = blockIdx.x, t = threadIdx.x;
  const int seg = (r >= 1920) ? 2 : (r >= 960 ? 1 : 0);
  const int sr = r - seg * 960;
  const float* W = (seg == 0) ? Wq : (seg == 1) ? Wk : Wv;
  const float sc = (seg == 0) ? scaleQ : 1.0f;
  if (t < 240) {
    f32x4 v = *(const f32x4*)(W + (size_t)sr * 960 + t * 4);
    u16x4 o;
    o[0] = f2bf(v[0] * sc); o[1] = f2bf(v[1] * sc);
    o[2] = f2bf(v[2] * sc); o[3] = f2bf(v[3] * sc);
    *(u16x4*)(Wqkv + (size_t)r * 1024 + t * 4) = o;
  } else {
    u16x4 z = {};
    *(u16x4*)(Wqkv + (size_t)r * 1024 + 960 + (t - 240) * 4) = z;
  }
  if (t == 0) {
    const float* bb = (seg == 0) ? bq : (seg == 1) ? bk : bv;
    biasQ[r] = bb[sr] * sc;
  }
}

// ---------------------------------------------------------------------------
// Gather-compact-cast: xc[b][j] = bf16(x[b][idx[b][j]]) for j < cnt[b];
// zero rows j in [cnt, ceil128(cnt)); 1024 cols (960 data + 64 zero pad).
// ---------------------------------------------------------------------------
__global__ __launch_bounds__(256) void compact_x(
    const float* __restrict__ x, const int* __restrict__ idx, const int* __restrict__ cnt,
    unsigned short* __restrict__ xc) {
  const int b = blockIdx.y;
  const int j = blockIdx.x * 4 + (threadIdx.x >> 6);
  const int l = threadIdx.x & 63;
  const int cb = cnt[b];
  const int cbc = (cb + 127) & ~127;
  if (j >= cbc) return;
  unsigned short* o = xc + ((size_t)b * 1024 + j) * 1024 + l * 16;
  bf16x8 o0 = {}, o1 = {};
  if (j < cb && l < 60) {
    const int s = idx[b * 1024 + j];
    const float* g = x + ((size_t)b * 1024 + s) * 960 + l * 16;
    f32x4 v0 = *(const f32x4*)(g);
    f32x4 v1 = *(const f32x4*)(g + 4);
    f32x4 v2 = *(const f32x4*)(g + 8);
    f32x4 v3 = *(const f32x4*)(g + 12);
    o0[0] = (short)f2bf(v0[0]); o0[1] = (short)f2bf(v0[1]);
    o0[2] = (short)f2bf(v0[2]); o0[3] = (short)f2bf(v0[3]);
    o0[4] = (short)f2bf(v1[0]); o0[5] = (short)f2bf(v1[1]);
    o0[6] = (short)f2bf(v1[2]); o0[7] = (short)f2bf(v1[3]);
    o1[0] = (short)f2bf(v2[0]); o1[1] = (short)f2bf(v2[1]);
    o1[2] = (short)f2bf(v2[2]); o1[3] = (short)f2bf(v2[3]);
    o1[4] = (short)f2bf(v3[0]); o1[5] = (short)f2bf(v3[1]);
    o1[6] = (short)f2bf(v3[2]); o1[7] = (short)f2bf(v3[3]);
  }
  *(bf16x8*)(o) = o0;
  *(bf16x8*)(o + 8) = o1;
}

// ---------------------------------------------------------------------------
// gemm128s: 128x128 NT GEMM, m97 structure (BK=32, single 16KB LDS, 4 waves,
// plain __syncthreads). (row>>1)&3 slot swizzle. Per-b compaction via cntArr.
// MODE 1: QKV epilogue (V-stores merged to u16x4).  MODE 2: bf16 out.
// ---------------------------------------------------------------------------
template <int MODE>
__global__ __launch_bounds__(256, 4) void gemm128s(
    const unsigned short* __restrict__ Ap, const unsigned short* __restrict__ Bp,
    int lda, int ldb, const float* __restrict__ bias,
    unsigned short* __restrict__ outC, unsigned short* __restrict__ outQ,
    unsigned short* __restrict__ outK, unsigned short* __restrict__ outV,
    int mTiles, int nTiles, int nktFixed, int ncols, int ldo,
    size_t aStride, size_t bStride, size_t oStride, const int* __restrict__ cntArr) {
  __shared__ unsigned short As[128 * 32];
  __shared__ unsigned short Bs[128 * 32];
  const int t = threadIdx.x, l = t & 63, w = t >> 6;
  const int wr = w >> 1, wc = w & 1;
  const int lq = l & 15, lh = l >> 4;

  const int nwg = (int)gridDim.x;
  const int flat = (int)blockIdx.x;
  const int q8 = nwg >> 3, r8 = nwg & 7, xcd = flat & 7;
  const int wgid = (xcd < r8 ? xcd * (q8 + 1) : r8 * (q8 + 1) + (xcd - r8) * q8) + (flat >> 3);
  const int pt = mTiles * nTiles;
  const int zb = wgid / pt;
  const int rm = wgid - zb * pt;
  const int mi = rm / nTiles;
  const int m0 = mi * 128;
  const int n0 = (rm - mi * nTiles) * 128;

  const int cb = cntArr[zb];
  if (m0 >= cb) return;
  const int nkt = (MODE == 2) ? ((cb + 31) >> 5) : nktFixed;

  const unsigned short* A = Ap + (size_t)zb * aStride + (size_t)m0 * lda;
  const unsigned short* B = Bp + (size_t)zb * bStride + (size_t)n0 * ldb;

  const int srow0 = w * 16 + (l >> 2);
  const int sg0 = l & 3;

  f32x4 acc[4][4] = {};
  for (int kt = 0; kt < nkt; ++kt) {
    const int d0 = kt * 32;
    __syncthreads();
#pragma unroll
    for (int p = 0; p < 2; ++p) {
      const int row = p * 64 + srow0;
      const int sg = sg0 ^ ((row >> 1) & 3);
      gload_lds16(A + (size_t)row * lda + d0 + sg * 8,
                  (char*)As + (size_t)(p * 64 + w * 16) * 64);
      gload_lds16(B + (size_t)row * ldb + d0 + sg * 8,
                  (char*)Bs + (size_t)(p * 64 + w * 16) * 64);
    }
    __syncthreads();
    bf16x8 aF[4], bF[4];
#pragma unroll
    for (int i = 0; i < 4; ++i) {
      const int rowA = 64 * wr + 16 * i + lq;
      aF[i] = *(const bf16x8*)(As + (size_t)rowA * 32 +
                               (size_t)(lh ^ ((rowA >> 1) & 3)) * 8);
      const int rowB = 64 * wc + 16 * i + lq;
      bF[i] = *(const bf16x8*)(Bs + (size_t)rowB * 32 +
                               (size_t)(lh ^ ((rowB >> 1) & 3)) * 8);
    }
#pragma unroll
    for (int i = 0; i < 4; ++i)
#pragma unroll
      for (int j = 0; j < 4; ++j) acc[i][j] = MFMA16(aF[i], bF[j], acc[i][j]);
  }

  // epilogue: C/D layout col = lane&15, row = (lane>>4)*4 + reg
  if (MODE == 2) {
#pragma unroll
    for (int j = 0; j < 4; ++j) {
      const int col = n0 + 64 * wc + 16 * j + lq;
      if (col >= ncols) continue;
#pragma unroll
      for (int i = 0; i < 4; ++i)
#pragma unroll
        for (int r = 0; r < 4; ++r) {
          const int row = m0 + 64 * wr + 16 * i + 4 * lh + r;
          outC[(size_t)zb * oStride + (size_t)row * ldo + col] = f2bf(acc[i][j][r]);
        }
    }
  } else {
#pragma unroll
    for (int j = 0; j < 4; ++j) {
      const int col = n0 + 64 * wc + 16 * j + lq;
      if (col >= ncols) continue;
      const int seg = (col >= 1920) ? 2 : (col >= 960 ? 1 : 0);
      const int dcol = col - seg * 960;
      const float bv = bias[col];
      if (seg == 2) {  // V: rows r=0..3 are consecutive in Vt -> one u16x4
#pragma unroll
        for (int i = 0; i < 4; ++i) {
          const int row = m0 + 64 * wr + 16 * i + 4 * lh;  // j within b
          u16x4 v4;
          v4[0] = f2bf(acc[i][j][0] + bv);
          v4[1] = f2bf(acc[i][j][1] + bv);
          v4[2] = f2bf(acc[i][j][2] + bv);
          v4[3] = f2bf(acc[i][j][3] + bv);
          *(u16x4*)(outV + ((size_t)zb << 20) + ((size_t)dcol << 10) + row) = v4;
        }
      } else {
#pragma unroll
        for (int i = 0; i < 4; ++i)
#pragma unroll
          for (int r = 0; r < 4; ++r) {
            const int row = m0 + 64 * wr + 16 * i + 4 * lh + r;
            const unsigned short v = f2bf(acc[i][j][r] + bv);
            if (seg == 0) outQ[((size_t)zb * 1024 + row) * 960 + dcol] = v;
            else outK[((size_t)zb * 1024 + row) * 960 + dcol] = v;
          }
      }
    }
  }
}

// ---------------------------------------------------------------------------
// NKS-templated attn K-loop. Specialized NKS in {3,4,5,6}: stage exactly NKS
// strips + 1 Q per wave, vmcnt(NKS+1). NKS==8 is the generic dummy-load
// fallback (stages 8 strips, dead ones duplicate strip 0; vmcnt(9)).
// ---------------------------------------------------------------------------
template <int NKS>
DEVINL void attn_kloop(const unsigned short* __restrict__ Kp,
                       const unsigned short* __restrict__ Qp,
                       unsigned short (*Ks)[1024 * 32], unsigned short (*Qs)[64 * 32],
                       int w, int lr, int sg0, int lq, int lh, int nks_rt,
                       f32x4 (&acc)[4][8]) {
#define STG(kkv, bufv)                                                        \
  {                                                                           \
    const int d0_ = (kkv) * 32;                                               \
    _Pragma("unroll") for (int i_ = 0; i_ < NKS; ++i_) {                      \
      const int br_ = i_ * 128 + w * 16;                                      \
      const int kr_ = (NKS == 8) ? ((i_ < nks_rt) ? (br_ + lr) : (w * 16 + lr)) \
                                 : (br_ + lr);                                \
      const int sg_ = sg0 ^ ((kr_ >> 1) & 3);                                 \
      gload_lds16(Kp + (size_t)kr_ * 960 + d0_ + sg_ * 8,                     \
                  (char*)Ks[(bufv)] + (size_t)br_ * 64);                      \
    }                                                                         \
    {                                                                         \
      const int qw_ = w & 3;                                                  \
      const int qr_ = qw_ * 16 + lr;                                          \
      const int sg_ = sg0 ^ ((qr_ >> 1) & 3);                                 \
      gload_lds16(Qp + (size_t)qr_ * 960 + d0_ + sg_ * 8,                     \
                  (char*)Qs[(bufv)] + (size_t)(qw_ * 16) * 64);               \
    }                                                                         \
  }
  STG(0, 0);
  int buf = 0;
  const int gate = (NKS == 8) ? nks_rt : NKS;
  for (int kk = 0; kk < 30; ++kk) {
    if (kk < 29) {
      STG(kk + 1, buf ^ 1);
      if constexpr (NKS == 3)      asm volatile("s_waitcnt vmcnt(4)" ::: "memory");
      else if constexpr (NKS == 4) asm volatile("s_waitcnt vmcnt(5)" ::: "memory");
      else if constexpr (NKS == 5) asm volatile("s_waitcnt vmcnt(6)" ::: "memory");
      else if constexpr (NKS == 6) asm volatile("s_waitcnt vmcnt(7)" ::: "memory");
      else                         asm volatile("s_waitcnt vmcnt(9)" ::: "memory");
    } else {
      asm volatile("s_waitcnt vmcnt(0)" ::: "memory");
    }
    __builtin_amdgcn_sched_barrier(0);
    __builtin_amdgcn_s_barrier();
    if (w < gate) {
      bf16x8 aF[4], bF[8];
#pragma unroll
      for (int i = 0; i < 4; ++i) {
        const int qr = 16 * i + lq;
        aF[i] = *(const bf16x8*)(Qs[buf] + qr * 32 + (lh ^ ((qr >> 1) & 3)) * 8);
      }
#pragma unroll
      for (int j = 0; j < 8; ++j) {
        const int kr = 128 * w + 16 * j + lq;
        bF[j] = *(const bf16x8*)(Ks[buf] + kr * 32 + (lh ^ ((kr >> 1) & 3)) * 8);
      }
#pragma unroll
      for (int i = 0; i < 4; ++i)
#pragma unroll
        for (int j = 0; j < 8; ++j) acc[i][j] = MFMA16(aF[i], bF[j], acc[i][j]);
    }
    __builtin_amdgcn_s_barrier();
    buf ^= 1;
  }
#undef STG
}

// ---------------------------------------------------------------------------
// Fused scores + masked softmax over COMPACTED rows, strip-skip + NKS staging.
// ---------------------------------------------------------------------------
__global__ __launch_bounds__(512, 2) void attn_softmax(
    const unsigned short* __restrict__ Qb, const unsigned short* __restrict__ Kb,
    const int* __restrict__ cnt, unsigned short* __restrict__ P) {
  __shared__ unsigned short Ks[2][1024 * 32];
  __shared__ unsigned short Qs[2][64 * 32];
  __shared__ float red[2][8][64];
  const int t = threadIdx.x, l = t & 63, w = t >> 6;
  const int flat = blockIdx.x;
  const int b = (flat & 7) * 4 + ((flat >> 3) >> 4);
  const int q0 = ((flat >> 3) & 15) * 64;
  const int cb = cnt[b];
  if (q0 >= cb) return;
  const int nks = (cb + 127) >> 7;
  const int lq = l & 15, lh = l >> 4;
  const unsigned short* Kp = Kb + (size_t)b * 1024 * 960;
  const unsigned short* Qp = Qb + ((size_t)b * 1024 + q0) * 960;
  const int lr = l >> 2, sg0 = l & 3;

  f32x4 acc[4][8] = {};
  if (nks == 4)      attn_kloop<4>(Kp, Qp, Ks, Qs, w, lr, sg0, lq, lh, nks, acc);
  else if (nks == 5) attn_kloop<5>(Kp, Qp, Ks, Qs, w, lr, sg0, lq, lh, nks, acc);
  else if (nks == 3) attn_kloop<3>(Kp, Qp, Ks, Qs, w, lr, sg0, lq, lh, nks, acc);
  else if (nks == 6) attn_kloop<6>(Kp, Qp, Ks, Qs, w, lr, sg0, lq, lh, nks, acc);
  else               attn_kloop<8>(Kp, Qp, Ks, Qs, w, lr, sg0, lq, lh, nks, acc);

  // compacted cols >= cnt -> -1e9 (covers dead waves entirely: acc was 0)
#pragma unroll
  for (int j = 0; j < 8; ++j) {
    const int k = 128 * w + 16 * j + lq;
    if (k >= cb) {
#pragma unroll
      for (int i = 0; i < 4; ++i)
#pragma unroll
        for (int r = 0; r < 4; ++r) acc[i][j][r] = -1e9f;
    }
  }

  float rmax[4][4];
#pragma unroll
  for (int i = 0; i < 4; ++i)
#pragma unroll
    for (int r = 0; r < 4; ++r) {
      float m = acc[i][0][r];
#pragma unroll
      for (int j = 1; j < 8; ++j) m = fmaxf(m, acc[i][j][r]);
      m = fmaxf(m, __shfl_xor(m, 1));
      m = fmaxf(m, __shfl_xor(m, 2));
      m = fmaxf(m, __shfl_xor(m, 4));
      m = fmaxf(m, __shfl_xor(m, 8));
      rmax[i][r] = m;
    }
  if (lq == 0) {
#pragma unroll
    for (int i = 0; i < 4; ++i)
#pragma unroll
      for (int r = 0; r < 4; ++r) red[0][w][16 * i + 4 * lh + r] = rmax[i][r];
  }
  __syncthreads();
#pragma unroll
  for (int i = 0; i < 4; ++i)
#pragma unroll
    for (int r = 0; r < 4; ++r) {
      const int rowi = 16 * i + 4 * lh + r;
      float m = red[0][0][rowi];
#pragma unroll
      for (int w2 = 1; w2 < 8; ++w2) m = fmaxf(m, red[0][w2][rowi]);
      rmax[i][r] = m;
    }

  float rsum[4][4];
#pragma unroll
  for (int i = 0; i < 4; ++i)
#pragma unroll
    for (int r = 0; r < 4; ++r) {
      float s = 0.f;
#pragma unroll
      for (int j = 0; j < 8; ++j) {
        const float e = __expf(acc[i][j][r] - rmax[i][r]);
        acc[i][j][r] = e;
        s += e;
      }
      s += __shfl_xor(s, 1); s += __shfl_xor(s, 2);
      s += __shfl_xor(s, 4); s += __shfl_xor(s, 8);
      rsum[i][r] = s;
    }
  if (lq == 0) {
#pragma unroll
    for (int i = 0; i < 4; ++i)
#pragma unroll
      for (int r = 0; r < 4; ++r) red[1][w][16 * i + 4 * lh + r] = rsum[i][r];
  }
  __syncthreads();

  if (w < nks) {  // dead waves' cols are never read by PV (>= ceil64(cnt))
    const size_t pb = ((size_t)b << 20) + (size_t)q0 * 1024;
#pragma unroll
    for (int i = 0; i < 4; ++i)
#pragma unroll
      for (int r = 0; r < 4; ++r) {
        const int rowi = 16 * i + 4 * lh + r;
        float s = 0.f;
#pragma unroll
        for (int w2 = 0; w2 < 8; ++w2) s += red[1][w2][rowi];
        const float inv = 1.0f / s;
#pragma unroll
        for (int j = 0; j < 8; ++j) {
          const int col = 128 * w + 16 * j + lq;
          P[pb + (size_t)rowi * 1024 + col] = f2bf(acc[i][j][r] * inv);
        }
      }
  }
}

// ---------------------------------------------------------------------------
// Compacted LN+pool.
// ---------------------------------------------------------------------------
__global__ __launch_bounds__(256) void ln_pool(
    const unsigned short* __restrict__ ctxb, const float* __restrict__ x,
    const int* __restrict__ idx, const int* __restrict__ cnt,
    const float* __restrict__ g, const float* __restrict__ bta,
    float* __restrict__ pooled) {
  const int b = blockIdx.y, chunk = blockIdx.x;
  const int w = threadIdx.x >> 6, l = threadIdx.x & 63;
  const int cb = cnt[b];
  f32x4 gc[4], bc[4];
#pragma unroll
  for (int c = 0; c < 4; ++c) {
    const int i4 = c * 64 + l;
    if (i4 < 240) {
      gc[c] = *(const f32x4*)(g + i4 * 4);
      bc[c] = *(const f32x4*)(bta + i4 * 4);
    }
  }
  f32x4 accp[4] = {};
  for (int rr = 0; rr < 8; ++rr) {
    const int j = chunk * 32 + w * 8 + rr;
    if (j >= cb) continue;
    const int sidx = idx[b * 1024 + j];
    const size_t cbase = ((size_t)b * 1024 + j) * 960;
    const size_t xbase = ((size_t)b * 1024 + sidx) * 960;
    f32x4 h[4];
    float part = 0.f;
#pragma unroll
    for (int c = 0; c < 4; ++c) {
      const int i4 = c * 64 + l;
      if (i4 < 240) {
        u16x4 cv = *(const u16x4*)(ctxb + cbase + (size_t)i4 * 4);
        f32x4 xv = *(const f32x4*)(x + xbase + (size_t)i4 * 4);
        h[c][0] = bf2f(cv[0]) + xv[0];
        h[c][1] = bf2f(cv[1]) + xv[1];
        h[c][2] = bf2f(cv[2]) + xv[2];
        h[c][3] = bf2f(cv[3]) + xv[3];
        part += h[c][0] + h[c][1] + h[c][2] + h[c][3];
      } else {
        h[c] = 0;
      }
    }
#pragma unroll
    for (int o = 1; o < 64; o <<= 1) part += __shfl_xor(part, o);
    const float mu = part * (1.0f / 960.0f);
    float p2 = 0.f;
#pragma unroll
    for (int c = 0; c < 4; ++c) {
      if (c * 64 + l < 240) {
#pragma unroll
        for (int k2 = 0; k2 < 4; ++k2) {
          const float d = h[c][k2] - mu;
          p2 += d * d;
        }
      }
    }
#pragma unroll
    for (int o = 1; o < 64; o <<= 1) p2 += __shfl_xor(p2, o);
    const float rs = rsqrtf(p2 * (1.0f / 960.0f) + 1e-5f);
#pragma unroll
    for (int c = 0; c < 4; ++c) {
      if (c * 64 + l < 240) {
#pragma unroll
        for (int k2 = 0; k2 < 4; ++k2)
          accp[c][k2] += (h[c][k2] - mu) * rs * gc[c][k2] + bc[c][k2];
      }
    }
  }
#pragma unroll
  for (int c = 0; c < 4; ++c) {
    const int i4 = c * 64 + l;
    if (i4 < 240) {
#pragma unroll
      for (int k2 = 0; k2 < 4; ++k2) atomicAdd(&pooled[b * 960 + i4 * 4 + k2], accp[c][k2]);
    }
  }
}

// ---------------------------------------------------------------------------
// pooled/cnt -> 960-512-256-128-10 MLP fp32.
// ---------------------------------------------------------------------------
__global__ __launch_bounds__(256) void mlp_head(
    const float* __restrict__ pooled, const int* __restrict__ cnt,
    const float* __restrict__ W1, const float* __restrict__ b1,
    const float* __restrict__ W2, const float* __restrict__ b2,
    const float* __restrict__ W3, const float* __restrict__ b3,
    const float* __restrict__ W4, const float* __restrict__ b4, float* __restrict__ out) {
  __shared__ float h0[960], h1[512], h2[256], h3[128];
  const int b = blockIdx.x, t = threadIdx.x;
  const float inv = 1.0f / fmaxf((float)cnt[b], 1e-9f);
  for (int d = t; d < 960; d += 256) h0[d] = pooled[b * 960 + d] * inv;
  __syncthreads();
  for (int o = t; o < 512; o += 256) {
    float a = b1[o];
    const float* wr = W1 + (size_t)o * 960;
    for (int k = 0; k < 960; k += 4) {
      f32x4 wv = *(const f32x4*)(wr + k);
      f32x4 hv = *(const f32x4*)(h0 + k);
      a += wv[0] * hv[0] + wv[1] * hv[1] + wv[2] * hv[2] + wv[3] * hv[3];
    }
    h1[o] = fmaxf(a, 0.f);
  }
  __syncthreads();
  {
    float a = b2[t];
    const float* wr = W2 + (size_t)t * 512;
    for (int k = 0; k < 512; k += 4) {
      f32x4 wv = *(const f32x4*)(wr + k);
      f32x4 hv = *(const f32x4*)(h1 + k);
      a += wv[0] * hv[0] + wv[1] * hv[1] + wv[2] * hv[2] + wv[3] * hv[3];
    }
    h2[t] = fmaxf(a, 0.f);
  }
  __syncthreads();
  if (t < 128) {
    float a = b3[t];
    const float* wr = W3 + (size_t)t * 256;
    for (int k = 0; k < 256; k += 4) {
      f32x4 wv = *(const f32x4*)(wr + k);
      f32x4 hv = *(const f32x4*)(h2 + k);
      a += wv[0] * hv[0] + wv[1] * hv[1] + wv[2] * hv[2] + wv[3] * hv[3];
    }
    h3[t] = fmaxf(a, 0.f);
  }
  __syncthreads();
  if (t < 10) {
    float a = b4[t];
    const float* wr = W4 + (size_t)t * 128;
    for (int k = 0; k < 128; ++k) a += wr[k] * h3[k];
    out[b * 10 + t] = a;
  }
}

// ---------------------------------------------------------------------------
// Workspace layout identical to rounds 8-11.
// ---------------------------------------------------------------------------
extern "C" void kernel_launch(void* const* d_in, const int* in_sizes, int n_in,
                              void* d_out, int out_size, void* d_ws, size_t ws_size,
                              hipStream_t stream) {
  (void)in_sizes; (void)n_in; (void)out_size; (void)ws_size;
  const float* x    = (const float*)d_in[0];
  const int*   mask = (const int*)d_in[1];
  const float* Wq   = (const float*)d_in[2];
  const float* bq   = (const float*)d_in[3];
  const float* Wk   = (const float*)d_in[4];
  const float* bk   = (const float*)d_in[5];
  const float* Wv   = (const float*)d_in[6];
  const float* bv   = (const float*)d_in[7];
  const float* lng  = (const float*)d_in[8];
  const float* lnb  = (const float*)d_in[9];
  const float* W1   = (const float*)d_in[10];
  const float* b1   = (const float*)d_in[11];
  const float* W2   = (const float*)d_in[12];
  const float* b2   = (const float*)d_in[13];
  const float* W3   = (const float*)d_in[14];
  const float* b3   = (const float*)d_in[15];
  const float* W4   = (const float*)d_in[16];
  const float* b4   = (const float*)d_in[17];
  float* out = (float*)d_out;

  char* ws = (char*)d_ws;
  unsigned short* xc     = (unsigned short*)(ws);
  unsigned short* P      = (unsigned short*)(ws);
  unsigned short* Qb     = (unsigned short*)(ws + 67108864);
  unsigned short* Kb     = (unsigned short*)(ws + 130023424);
  unsigned short* ctxb   = (unsigned short*)(ws + 67108864);
  unsigned short* Vt     = (unsigned short*)(ws + 192937984);
  unsigned short* Wqkv   = (unsigned short*)(ws + 260046848);
  float*          biasQ  = (float*)(ws + 266338304);
  float*          pooled = (float*)(ws + 266349824);
  int*            cntW   = (int*)(ws + 266472704);
  int*            idxW   = (int*)(ws + 266472832);

  const float scaleQ = 0.0322748612183951f;  // 1/sqrt(960)

  scan_mask<<<32, 256, 0, stream>>>(mask, idxW, cntW);
  cast_wqkv<<<2880, 256, 0, stream>>>(Wq, Wk, Wv, bq, bk, bv, Wqkv, biasQ, scaleQ);
  compact_x<<<dim3(256, 32), 256, 0, stream>>>(x, idxW, cntW, xc);

  // fused QKV: per b, M = ceil128(cnt[b]) (early-exit), N = 2880, K = 960
  gemm128s<1><<<32 * 8 * 23, 256, 0, stream>>>(
      xc, Wqkv, 1024, 1024, biasQ, nullptr, Qb, Kb, Vt,
      8, 23, 30, 2880, 0, (size_t)1048576, 0, 0, cntW);

  attn_softmax<<<512, 512, 0, stream>>>(Qb, Kb, cntW, P);

  // ctx[b] = P[b] . Vt[b]^T : M = ceil128(cnt), N=960, K = ceil32(cnt)
  gemm128s<2><<<8 * 8 * 32, 256, 0, stream>>>(
      P, Vt, 1024, 1024, nullptr, ctxb, nullptr, nullptr, nullptr,
      8, 8, 0, 960, 960, (size_t)1048576, (size_t)1048576, (size_t)983040, cntW);

  hipMemsetAsync(pooled, 0, 32 * 960 * 4, stream);
  ln_pool<<<dim3(32, 32), 256, 0, stream>>>(ctxb, x, idxW, cntW, lng, lnb, pooled);
  mlp_head<<<32, 256, 0, stream>>>(pooled, cntW, W1, b1, W2, b2, W3, b3, W4, b4, out);
}